// Round 5
// baseline (1474.039 us; speedup 1.0000x reference)
//
#include <hip/hip_runtime.h>
#include <cstddef>

// Problem constants
#define TT    32       // T_ENC
#define DD    512      // D_IN
#define HH    256      // hidden
#define NCLS  38       // classes
#define NSTEP 26       // MAXLEN+1
#define KX    576      // padded x-part K (512 ctx + 38 onehot + 26 pad) = 18*32
#define KTOT  832      // KX + HH
#define NKC   26       // K chunks of 32 for gates GEMM
#define XCH   34       // XSW chunk count: 18 x-chunks + 8 h(even) + 8 h(odd)

typedef float f32x4 __attribute__((ext_vector_type(4)));
typedef short bf16x8 __attribute__((ext_vector_type(8)));

union cv8 { uint4 u; bf16x8 v; };

__device__ __forceinline__ float fast_tanh(float z) {
  float e = __expf(2.f * z);
  return 1.f - 2.f / (e + 1.f);
}
__device__ __forceinline__ float fast_sigmoid(float z) {
  return 1.f / (1.f + __expf(-z));
}
__device__ __forceinline__ float bf2f(unsigned short s) {
  union { unsigned int u; float f; } v; v.u = ((unsigned int)s) << 16; return v.f;
}
__device__ __forceinline__ unsigned short f2bf(float f) {  // RNE
  union { float ff; unsigned int u; } v; v.ff = f;
  unsigned int r = v.u + 0x7FFFu + ((v.u >> 16) & 1u);
  return (unsigned short)(r >> 16);
}
__device__ __forceinline__ unsigned int pk(unsigned short a, unsigned short b) {
  return (unsigned int)a | ((unsigned int)b << 16);
}

// ---------------------------------------------------------------------------
// gates weights: [W_ihP(576) | W_hh(256)] bf16, gate-interleaved cols, MFMA-B swizzled.
__global__ __launch_bounds__(256) void prep_wg_kernel(const float* __restrict__ W_ih,
                                                      const float* __restrict__ W_hh,
                                                      unsigned short* __restrict__ Wg) {
  int flat = blockIdx.x * 256 + threadIdx.x;   // 64*NKC*64 = 106496
  if (flat >= 64 * NKC * 64) return;
  int l = flat & 63, ntkc = flat >> 6;
  int nt = ntkc / NKC, kc = ntkc - nt * NKC;
  int col = nt * 16 + (l & 15);
  int gate = (col >> 6) & 3;
  int jg = (col >> 8) * 64 + (col & 63);
  int orig = gate * 256 + jg;
  int kbase = kc * 32 + (l >> 4) * 8;
  unsigned short e[8];
#pragma unroll
  for (int j = 0; j < 8; ++j) {
    int k = kbase + j;
    float v;
    if (k < DD + NCLS)      v = W_ih[orig * (DD + NCLS) + k];
    else if (k < KX)        v = 0.f;
    else                    v = W_hh[orig * HH + (k - KX)];
    e[j] = f2bf(v);
  }
  uint4 o = {pk(e[0], e[1]), pk(e[2], e[3]), pk(e[4], e[5]), pk(e[6], e[7])};
  ((uint4*)Wg)[flat] = o;
}

// W_i2h [256][512] -> bf16 MFMA-B swizzled [nt(16)][kc(16)][lane][8]
__global__ __launch_bounds__(256) void prep_wi_kernel(const float* __restrict__ W_i2h,
                                                      unsigned short* __restrict__ Wi) {
  int flat = blockIdx.x * 256 + threadIdx.x;   // 16*16*64 = 16384
  int l = flat & 63, ntkc = flat >> 6;
  int nt = ntkc >> 4, kc = ntkc & 15;
  int n = nt * 16 + (l & 15);
  int kbase = kc * 32 + (l >> 4) * 8;
  unsigned short e[8];
#pragma unroll
  for (int j = 0; j < 8; ++j) e[j] = f2bf(W_i2h[(size_t)n * DD + kbase + j]);
  uint4 o = {pk(e[0], e[1]), pk(e[2], e[3]), pk(e[4], e[5]), pk(e[6], e[7])};
  ((uint4*)Wi)[flat] = o;
}

// W_gen [38][256] -> bf16 MFMA-B swizzled [nt(3)][kc(8)][lane][8], cols padded to 48
__global__ __launch_bounds__(256) void prep_wgen_kernel(const float* __restrict__ W_gen,
                                                        unsigned short* __restrict__ Wgp) {
  int flat = blockIdx.x * 256 + threadIdx.x;   // 3*8*64 = 1536
  if (flat >= 1536) return;
  int l = flat & 63, ntkc = flat >> 6;
  int nt = ntkc >> 3, kc = ntkc & 7;
  int n = nt * 16 + (l & 15);
  int kbase = kc * 32 + (l >> 4) * 8;
  unsigned short e[8];
#pragma unroll
  for (int j = 0; j < 8; ++j)
    e[j] = (n < NCLS) ? f2bf(W_gen[(size_t)n * HH + kbase + j]) : (unsigned short)0;
  uint4 o = {pk(e[0], e[1]), pk(e[2], e[3]), pk(e[4], e[5]), pk(e[6], e[7])};
  ((uint4*)Wgp)[flat] = o;
}

// W_h2h [256][256] -> bf16 MFMA-B swizzled [nt(16)][kc(8)][lane][8]; plus bc = b_ih+b_hh
__global__ __launch_bounds__(256) void prep_whb_bc_kernel(const float* __restrict__ W_h2h,
                                                          const float* __restrict__ b_ih,
                                                          const float* __restrict__ b_hh,
                                                          unsigned short* __restrict__ Whb,
                                                          float* __restrict__ bc) {
  int flat = blockIdx.x * 256 + threadIdx.x;   // 16*8*64 = 8192
  if (flat >= 8192) return;
  int l = flat & 63, ntkc = flat >> 6;
  int nt = ntkc >> 3, kc = ntkc & 7;
  int n = nt * 16 + (l & 15);
  int kbase = kc * 32 + (l >> 4) * 8;
  unsigned short e[8];
#pragma unroll
  for (int j = 0; j < 8; ++j) e[j] = f2bf(W_h2h[(size_t)n * HH + kbase + j]);
  uint4 o = {pk(e[0], e[1]), pk(e[2], e[3]), pk(e[4], e[5]), pk(e[6], e[7])};
  ((uint4*)Whb)[flat] = o;
  if (flat < 1024) bc[flat] = b_ih[flat] + b_hh[flat];
}

// zero cbuf + XSW h-even chunks (18..25)
__global__ __launch_bounds__(256) void init_zero_kernel(float* __restrict__ cbuf,
                                                        unsigned short* __restrict__ XSW) {
  int flat = blockIdx.x * 256 + threadIdx.x;   // 196608
  if (flat < 131072) {
    float4 z = {0.f, 0.f, 0.f, 0.f};
    ((float4*)cbuf)[flat] = z;
  } else {
    int j = flat - 131072;            // 128 mt * 8 kc * 64 lanes
    int mt = j >> 9, rem = j & 511;
    int kc = 18 + (rem >> 6), lane = rem & 63;
    uint4 zz = {0u, 0u, 0u, 0u};
    ((uint4*)XSW)[((size_t)mt * XCH + kc) * 64 + lane] = zz;
  }
}

// ---------------------------------------------------------------------------
// Merged: batch_H fp32 -> bHbf (bf16 row-major) AND H_proj = bH @ W_i2h^T -> Hbf.
// 512 blocks * 128 rows.
__global__ __launch_bounds__(256) void hproj_cvt_kernel(const float* __restrict__ src,
                                                        const unsigned short* __restrict__ Wi,
                                                        unsigned short* __restrict__ bHbf,
                                                        unsigned short* __restrict__ Hbf) {
  const int tid = threadIdx.x;
  const int w = tid >> 6, l = tid & 63;
  const int li = l & 15, qd = l >> 4;
  const int m0 = blockIdx.x * 128 + w * 32;
  f32x4 acc[2][16];
#pragma unroll
  for (int a = 0; a < 2; ++a)
#pragma unroll
    for (int b = 0; b < 16; ++b) acc[a][b] = (f32x4){0.f, 0.f, 0.f, 0.f};
  const bf16x8* Wi8 = (const bf16x8*)Wi;
  for (int kc = 0; kc < 16; ++kc) {
    const int col = kc * 32 + qd * 8;
    const float* p0 = src + (size_t)(m0 + li) * DD + col;
    const float* p1 = src + (size_t)(m0 + 16 + li) * DD + col;
    float4 x0a = ((const float4*)p0)[0], x0b = ((const float4*)p0)[1];
    float4 x1a = ((const float4*)p1)[0], x1b = ((const float4*)p1)[1];
    cv8 a0, a1;
    a0.u = (uint4){pk(f2bf(x0a.x), f2bf(x0a.y)), pk(f2bf(x0a.z), f2bf(x0a.w)),
                   pk(f2bf(x0b.x), f2bf(x0b.y)), pk(f2bf(x0b.z), f2bf(x0b.w))};
    a1.u = (uint4){pk(f2bf(x1a.x), f2bf(x1a.y)), pk(f2bf(x1a.z), f2bf(x1a.w)),
                   pk(f2bf(x1b.x), f2bf(x1b.y)), pk(f2bf(x1b.z), f2bf(x1b.w))};
    *(uint4*)(bHbf + (size_t)(m0 + li) * DD + col) = a0.u;
    *(uint4*)(bHbf + (size_t)(m0 + 16 + li) * DD + col) = a1.u;
#pragma unroll
    for (int nt = 0; nt < 16; ++nt) {
      bf16x8 b = Wi8[(nt * 16 + kc) * 64 + l];
      acc[0][nt] = __builtin_amdgcn_mfma_f32_16x16x32_bf16(a0.v, b, acc[0][nt], 0, 0, 0);
      acc[1][nt] = __builtin_amdgcn_mfma_f32_16x16x32_bf16(a1.v, b, acc[1][nt], 0, 0, 0);
    }
  }
#pragma unroll
  for (int mi = 0; mi < 2; ++mi)
#pragma unroll
    for (int nt = 0; nt < 16; ++nt)
#pragma unroll
      for (int r = 0; r < 4; ++r) {
        int row = m0 + mi * 16 + qd * 4 + r;
        Hbf[(size_t)row * HH + nt * 16 + li] = f2bf(acc[mi][nt][r]);
      }
}

// ---------------------------------------------------------------------------
// fused per-step: hp via MFMA + attention + context. 512 blocks * 4 batch rows.
__global__ __launch_bounds__(256) void attn_fused_kernel(
    const unsigned short* __restrict__ Hbf, const unsigned short* __restrict__ bHbf,
    const unsigned short* __restrict__ XSWr, const unsigned short* __restrict__ Whb,
    const float* __restrict__ b_h2h, const float* __restrict__ W_score,
    const int* __restrict__ text, unsigned short* __restrict__ XSW, int s, int hb_r) {
  __shared__ float sh_hp[4][HH];
  __shared__ float sh_ws[HH];
  __shared__ float sh_e[4][TT];
  const int tid = threadIdx.x;
  const int b0 = blockIdx.x * 4;
  const int w = tid >> 6, ln = tid & 63;
  const int li = ln & 15, qd = ln >> 4;

  if (tid < HH / 4) ((float4*)sh_ws)[tid] = ((const float4*)W_score)[tid];

  // onehot + zero pad -> XSW chunks 16..17 (independent of everything; do early)
  if (tid >= 64 && tid < 96) {
    int t2 = tid - 64;
    int i = t2 >> 3, k0 = DD + (t2 & 7) * 8;
    int row = b0 + i;
    int ch = text[row * NSTEP + s];
    unsigned short e8[8];
#pragma unroll
    for (int j = 0; j < 8; ++j) e8[j] = (k0 + j - DD == ch) ? (unsigned short)0x3F80 : (unsigned short)0;
    uint4 o = {pk(e8[0], e8[1]), pk(e8[2], e8[3]), pk(e8[4], e8[5]), pk(e8[6], e8[7])};
    int lane_t = ((k0 & 31) >> 3) * 16 + (row & 15);
    ((uint4*)XSW)[((size_t)(row >> 4) * XCH + (k0 >> 5)) * 64 + lane_t] = o;
  }

  // hp tile via MFMA: 16-row tile mt contains our 4 rows; wave w covers cols w*64..+63
  {
    const int mt = blockIdx.x >> 2;
    const int qsel = (b0 & 15) >> 2;
    f32x4 hacc[4];
#pragma unroll
    for (int n = 0; n < 4; ++n) hacc[n] = (f32x4){0.f, 0.f, 0.f, 0.f};
    const bf16x8* X8 = (const bf16x8*)XSWr;
    const bf16x8* WB = (const bf16x8*)Whb;
#pragma unroll
    for (int kc = 0; kc < 8; ++kc) {
      bf16x8 a = X8[((size_t)mt * XCH + hb_r + kc) * 64 + ln];
#pragma unroll
      for (int n = 0; n < 4; ++n) {
        bf16x8 b = WB[((w * 4 + n) * 8 + kc) * 64 + ln];
        hacc[n] = __builtin_amdgcn_mfma_f32_16x16x32_bf16(a, b, hacc[n], 0, 0, 0);
      }
    }
    if (qd == qsel) {
#pragma unroll
      for (int n = 0; n < 4; ++n) {
        int col = (w * 4 + n) * 16 + li;
        float bb = b_h2h[col];
#pragma unroll
        for (int r = 0; r < 4; ++r) sh_hp[r][col] = hacc[n][r] + bb;
      }
    }
  }
  __syncthreads();

  // e[i][t]: 2 threads per (i,t) pair; each covers 128 j's via 16 independent loads
  {
    const int p = tid >> 1, half = tid & 1;
    const int i = p >> 5, t = p & 31;
    const unsigned short* hb = Hbf + ((size_t)(b0 + i) * TT + t) * HH + half * 128;
    float v = 0.f;
#pragma unroll
    for (int c = 0; c < 16; ++c) {
      uint4 hv = *(const uint4*)(hb + c * 8);
      int j = half * 128 + c * 8;
      float4 hp0 = *(const float4*)&sh_hp[i][j];
      float4 hp1 = *(const float4*)&sh_hp[i][j + 4];
      float4 ws0 = *(const float4*)&sh_ws[j];
      float4 ws1 = *(const float4*)&sh_ws[j + 4];
      v += fast_tanh(bf2f((unsigned short)(hv.x & 0xFFFF)) + hp0.x) * ws0.x;
      v += fast_tanh(bf2f((unsigned short)(hv.x >> 16))    + hp0.y) * ws0.y;
      v += fast_tanh(bf2f((unsigned short)(hv.y & 0xFFFF)) + hp0.z) * ws0.z;
      v += fast_tanh(bf2f((unsigned short)(hv.y >> 16))    + hp0.w) * ws0.w;
      v += fast_tanh(bf2f((unsigned short)(hv.z & 0xFFFF)) + hp1.x) * ws1.x;
      v += fast_tanh(bf2f((unsigned short)(hv.z >> 16))    + hp1.y) * ws1.y;
      v += fast_tanh(bf2f((unsigned short)(hv.w & 0xFFFF)) + hp1.z) * ws1.z;
      v += fast_tanh(bf2f((unsigned short)(hv.w >> 16))    + hp1.w) * ws1.w;
    }
    v += __shfl_xor(v, 1, 64);
    if (half == 0) sh_e[i][t] = v;
  }
  __syncthreads();

  // softmax over t (32-lane groups = one row); threads 0..127
  if (tid < 128) {
    int i = tid >> 5, t = tid & 31;
    float e = sh_e[i][t];
    float mx = e;
#pragma unroll
    for (int m = 16; m >= 1; m >>= 1) mx = fmaxf(mx, __shfl_xor(mx, m, 32));
    float pexp = __expf(e - mx);
    float ssum = pexp;
#pragma unroll
    for (int m = 16; m >= 1; m >>= 1) ssum += __shfl_xor(ssum, m, 32);
    sh_e[i][t] = pexp / ssum;
  }
  __syncthreads();

  // context -> XSW chunks 0..15 (swizzled bf16); thread owns row i, 8 d's
  {
    int i = tid >> 6, d0 = (tid & 63) * 8;
    int row = b0 + i;
    float acc[8] = {0.f, 0.f, 0.f, 0.f, 0.f, 0.f, 0.f, 0.f};
    const unsigned short* bh = bHbf + (size_t)row * TT * DD + d0;
#pragma unroll
    for (int t = 0; t < TT; ++t) {
      float a = sh_e[i][t];
      uint4 hv = *(const uint4*)(bh + (size_t)t * DD);
      acc[0] += a * bf2f((unsigned short)(hv.x & 0xFFFF));
      acc[1] += a * bf2f((unsigned short)(hv.x >> 16));
      acc[2] += a * bf2f((unsigned short)(hv.y & 0xFFFF));
      acc[3] += a * bf2f((unsigned short)(hv.y >> 16));
      acc[4] += a * bf2f((unsigned short)(hv.z & 0xFFFF));
      acc[5] += a * bf2f((unsigned short)(hv.z >> 16));
      acc[6] += a * bf2f((unsigned short)(hv.w & 0xFFFF));
      acc[7] += a * bf2f((unsigned short)(hv.w >> 16));
    }
    uint4 o = {pk(f2bf(acc[0]), f2bf(acc[1])), pk(f2bf(acc[2]), f2bf(acc[3])),
               pk(f2bf(acc[4]), f2bf(acc[5])), pk(f2bf(acc[6]), f2bf(acc[7]))};
    int lane_t = ((d0 & 31) >> 3) * 16 + (row & 15);
    ((uint4*)XSW)[((size_t)(row >> 4) * XCH + (d0 >> 5)) * 64 + lane_t] = o;
  }
}

// ---------------------------------------------------------------------------
// gates MFMA + LSTM cell. grid (4 cg, 32 mg); block = 64 rows x 256 gate-cols.
__global__ __launch_bounds__(256) void lstm_mfma_kernel(
    const unsigned short* __restrict__ XSW, const unsigned short* __restrict__ Wg,
    const float* __restrict__ bc, float* __restrict__ cbuf,
    unsigned short* __restrict__ hbf_out, unsigned short* __restrict__ XSWw,
    int hb_r, int hb_w) {
  const int tid = threadIdx.x;
  const int w = tid >> 6, l = tid & 63;
  const int li = l & 15, qd = l >> 4;
  const int cg = blockIdx.x;
  const int m0 = blockIdx.y * 64;
  const int mt0 = m0 >> 4;
  f32x4 acc[4][4];
#pragma unroll
  for (int a = 0; a < 4; ++a)
#pragma unroll
    for (int g = 0; g < 4; ++g) acc[a][g] = (f32x4){0.f, 0.f, 0.f, 0.f};
  const bf16x8* X8 = (const bf16x8*)XSW;
  const bf16x8* W8 = (const bf16x8*)Wg;
  for (int kc = 0; kc < NKC; ++kc) {
    int skc = (kc < 18) ? kc : (hb_r + (kc - 18));
    bf16x8 a0 = X8[((size_t)(mt0 + 0) * XCH + skc) * 64 + l];
    bf16x8 a1 = X8[((size_t)(mt0 + 1) * XCH + skc) * 64 + l];
    bf16x8 a2 = X8[((size_t)(mt0 + 2) * XCH + skc) * 64 + l];
    bf16x8 a3 = X8[((size_t)(mt0 + 3) * XCH + skc) * 64 + l];
#pragma unroll
    for (int g = 0; g < 4; ++g) {
      bf16x8 b = W8[((size_t)(cg * 16 + g * 4 + w) * NKC + kc) * 64 + l];
      acc[0][g] = __builtin_amdgcn_mfma_f32_16x16x32_bf16(a0, b, acc[0][g], 0, 0, 0);
      acc[1][g] = __builtin_amdgcn_mfma_f32_16x16x32_bf16(a1, b, acc[1][g], 0, 0, 0);
      acc[2][g] = __builtin_amdgcn_mfma_f32_16x16x32_bf16(a2, b, acc[2][g], 0, 0, 0);
      acc[3][g] = __builtin_amdgcn_mfma_f32_16x16x32_bf16(a3, b, acc[3][g], 0, 0, 0);
    }
  }
  const int jg = cg * 64 + w * 16 + li;
  float bcv[4];
#pragma unroll
  for (int g = 0; g < 4; ++g) bcv[g] = bc[g * 256 + jg];
#pragma unroll
  for (int mi = 0; mi < 4; ++mi)
#pragma unroll
    for (int r = 0; r < 4; ++r) {
      int row = m0 + mi * 16 + qd * 4 + r;
      float iv = fast_sigmoid(acc[mi][0][r] + bcv[0]);
      float fv = fast_sigmoid(acc[mi][1][r] + bcv[1]);
      float gv = fast_tanh   (acc[mi][2][r] + bcv[2]);
      float ov = fast_sigmoid(acc[mi][3][r] + bcv[3]);
      float cold = cbuf[(size_t)row * HH + jg];
      float cn = fv * cold + iv * gv;
      float hn = ov * fast_tanh(cn);
      cbuf[(size_t)row * HH + jg] = cn;
      unsigned short hb = f2bf(hn);
      hbf_out[(size_t)row * HH + jg] = hb;
      int kcx = hb_w + (jg >> 5);
      int k2 = jg & 31;
      XSWw[((size_t)(row >> 4) * XCH + kcx) * 512 + ((k2 >> 3) * 16 + (row & 15)) * 8 + (k2 & 7)] = hb;
    }
}

// ---------------------------------------------------------------------------
// probs via MFMA: rows r = s*2048+b of hidbf, N=48 (38 used). 416 blocks * 128 rows.
__global__ __launch_bounds__(256) void probs_mfma_kernel(
    const unsigned short* __restrict__ hidbf, const unsigned short* __restrict__ Wgp,
    const float* __restrict__ b_gen, float* __restrict__ out) {
  const int tid = threadIdx.x;
  const int w = tid >> 6, l = tid & 63;
  const int li = l & 15, qd = l >> 4;
  const int m0 = blockIdx.x * 128 + w * 32;
  f32x4 acc[2][3];
#pragma unroll
  for (int a = 0; a < 2; ++a)
#pragma unroll
    for (int n = 0; n < 3; ++n) acc[a][n] = (f32x4){0.f, 0.f, 0.f, 0.f};
  const bf16x8* W8 = (const bf16x8*)Wgp;
#pragma unroll
  for (int kc = 0; kc < 8; ++kc) {
    bf16x8 a0 = *(const bf16x8*)(hidbf + (size_t)(m0 + li) * HH + kc * 32 + qd * 8);
    bf16x8 a1 = *(const bf16x8*)(hidbf + (size_t)(m0 + 16 + li) * HH + kc * 32 + qd * 8);
#pragma unroll
    for (int nt = 0; nt < 3; ++nt) {
      bf16x8 b = W8[(nt * 8 + kc) * 64 + l];
      acc[0][nt] = __builtin_amdgcn_mfma_f32_16x16x32_bf16(a0, b, acc[0][nt], 0, 0, 0);
      acc[1][nt] = __builtin_amdgcn_mfma_f32_16x16x32_bf16(a1, b, acc[1][nt], 0, 0, 0);
    }
  }
  float bg[3];
#pragma unroll
  for (int nt = 0; nt < 3; ++nt) {
    int col = nt * 16 + li;
    bg[nt] = (col < NCLS) ? b_gen[col] : 0.f;
  }
#pragma unroll
  for (int mi = 0; mi < 2; ++mi)
#pragma unroll
    for (int nt = 0; nt < 3; ++nt) {
      int col = nt * 16 + li;
      if (col < NCLS) {
#pragma unroll
        for (int r = 0; r < 4; ++r) {
          int row = m0 + mi * 16 + qd * 4 + r;
          int s = row >> 11, b = row & 2047;
          out[((size_t)b * NSTEP + s) * NCLS + col] = acc[mi][nt][r] + bg[nt];
        }
      }
    }
}

// ---------------------------------------------------------------------------
extern "C" void kernel_launch(void* const* d_in, const int* in_sizes, int n_in,
                              void* d_out, int out_size, void* d_ws, size_t ws_size,
                              hipStream_t stream) {
  const float* batch_H = (const float*)d_in[0];
  const int*   text    = (const int*)d_in[1];
  const float* W_i2h   = (const float*)d_in[2];
  const float* W_h2h   = (const float*)d_in[3];
  const float* b_h2h   = (const float*)d_in[4];
  const float* W_score = (const float*)d_in[5];
  const float* W_ih    = (const float*)d_in[6];
  const float* b_ih    = (const float*)d_in[7];
  const float* W_hh    = (const float*)d_in[8];
  const float* b_hh    = (const float*)d_in[9];
  const float* W_gen   = (const float*)d_in[10];
  const float* b_gen   = (const float*)d_in[11];
  float* out = (float*)d_out;

  // workspace layout (bytes)
  char* p = (char*)d_ws;
  unsigned short* bHbf = (unsigned short*)p;              p += (size_t)2048 * 32 * 512 * 2;   // 64 MiB
  unsigned short* Hbf  = (unsigned short*)p;              p += (size_t)65536 * 256 * 2;       // 32 MiB
  unsigned short* hidbf= (unsigned short*)p;              p += (size_t)26 * 2048 * 256 * 2;   // 26 MiB
  float* cbuf          = (float*)p;                       p += (size_t)2048 * 256 * 4;
  unsigned short* XSW  = (unsigned short*)p;              p += (size_t)2048 * (XCH * 32) * 2;
  unsigned short* Wg   = (unsigned short*)p;              p += (size_t)1024 * KTOT * 2;
  unsigned short* Wi   = (unsigned short*)p;              p += (size_t)256 * 512 * 2;
  unsigned short* Wgp  = (unsigned short*)p;              p += (size_t)3 * 8 * 64 * 8 * 2;
  unsigned short* Whb  = (unsigned short*)p;              p += (size_t)16 * 8 * 64 * 8 * 2;
  float* bc            = (float*)p;                       p += (size_t)1024 * 4;

  prep_wg_kernel<<<416, 256, 0, stream>>>(W_ih, W_hh, Wg);
  prep_wi_kernel<<<64, 256, 0, stream>>>(W_i2h, Wi);
  prep_wgen_kernel<<<6, 256, 0, stream>>>(W_gen, Wgp);
  prep_whb_bc_kernel<<<32, 256, 0, stream>>>(W_h2h, b_ih, b_hh, Whb, bc);
  init_zero_kernel<<<768, 256, 0, stream>>>(cbuf, XSW);

  hproj_cvt_kernel<<<512, 256, 0, stream>>>(batch_H, Wi, bHbf, Hbf);

  for (int s = 0; s < NSTEP; ++s) {
    unsigned short* hbf_s = hidbf + (size_t)s * 2048 * 256;
    int hb_r = 18 + 8 * (s & 1);
    int hb_w = 18 + 8 * ((s + 1) & 1);
    attn_fused_kernel<<<512, 256, 0, stream>>>(Hbf, bHbf, XSW, Whb, b_h2h, W_score,
                                               text, XSW, s, hb_r);
    lstm_mfma_kernel<<<dim3(4, 32), 256, 0, stream>>>(XSW, Wg, bc, cbuf,
                                                      hbf_s, XSW, hb_r, hb_w);
  }

  probs_mfma_kernel<<<416, 256, 0, stream>>>(hidbf, Wgp, b_gen, out);
}